// Round 5
// baseline (124.005 us; speedup 1.0000x reference)
//
#include <hip/hip_runtime.h>
#include <math.h>

#define NCLS 9
#define DIM 768
#define NPIX 65536   // 4 * 128 * 128

// ---- workspace layout (bytes), no memset needed ----
#define OFF_LAB     ((size_t)0)        // uchar[65536]          = 65536
#define OFF_HIST    ((size_t)65536)    // int[256*9]            = 9216   -> 74752
#define OFF_SUMS    ((size_t)74752)    // float[9*768]          = 27648  -> 102400
#define OFF_SUMSQ   ((size_t)102400)   // float[16] (zeroed by k0)
#define OFF_LOSS    ((size_t)102464)   // float[4]  (zeroed by k0)
#define OFF_DONE    ((size_t)102480)   // uint[4]   (zeroed by k0, k5 ticket)
#define OFF_LOGITS  ((size_t)139392)   // float[9*65536]        = 2359296 -> 2498688
// total ~2.5 MB

__device__ __forceinline__ float waveReduceSum(float v) {
#pragma unroll
  for (int off = 32; off > 0; off >>= 1) v += __shfl_down(v, off, 64);
  return v;
}

// K0: downsample labels -> uchar lab[n]; per-block histogram -> hist[block][9];
// block 0 zero-inits sumsq/lossacc/done for downstream kernels.
__global__ void k0_lab(const int* __restrict__ label, unsigned char* __restrict__ lab,
                       int* __restrict__ hist, float* __restrict__ sumsq,
                       float* __restrict__ lossacc, unsigned int* __restrict__ done) {
  __shared__ int h[NCLS];
  int tid = threadIdx.x;
  if (tid < NCLS) h[tid] = 0;
  __syncthreads();
  int n = blockIdx.x * 256 + tid;
  int b = n >> 14, r = (n >> 7) & 127, cc = n & 127;
  int c = label[b * 262144 + r * 2048 + cc * 4];
  lab[n] = (unsigned char)c;
  atomicAdd(&h[c], 1);
  if (blockIdx.x == 0) {
    if (tid < 16) sumsq[tid] = 0.f;
    else if (tid == 16) lossacc[0] = 0.f;
    else if (tid == 17) done[0] = 0u;
  }
  __syncthreads();
  if (tid < NCLS) hist[blockIdx.x * NCLS + tid] = h[tid];
}

// K1: per-class segment sums. One block per feature dim d. Pure streaming — NO
// fences/tickets here (agent-scope __threadfence in every block was a 5x
// slowdown in R2: forces L2 writebacks on non-coherent XCD L2s).
__global__ void k1_segsum(const float4* __restrict__ feat4, const uchar4* __restrict__ lab4,
                          float* __restrict__ sums) {
  int d = blockIdx.x;
  int tid = threadIdx.x;
  float acc[NCLS];
#pragma unroll
  for (int k = 0; k < NCLS; ++k) acc[k] = 0.f;
  for (int b = 0; b < 4; ++b) {
    const float4* fp = feat4 + (size_t)(b * DIM + d) * 4096;
    const uchar4* lp = lab4 + b * 4096;
#pragma unroll 4
    for (int i = 0; i < 16; ++i) {
      int p = tid + i * 256;
      float4 f = fp[p];
      uchar4 l = lp[p];
      int lx = l.x, ly = l.y, lz = l.z, lw = l.w;
#pragma unroll
      for (int k = 0; k < NCLS; ++k) {
        acc[k] += (lx == k) ? f.x : 0.f;
        acc[k] += (ly == k) ? f.y : 0.f;
        acc[k] += (lz == k) ? f.z : 0.f;
        acc[k] += (lw == k) ? f.w : 0.f;
      }
    }
  }
  __shared__ float red[4][NCLS];
#pragma unroll
  for (int k = 0; k < NCLS; ++k) acc[k] = waveReduceSum(acc[k]);
  int lane = tid & 63, w = tid >> 6;
  if (lane == 0) {
#pragma unroll
    for (int k = 0; k < NCLS; ++k) red[w][k] = acc[k];
  }
  __syncthreads();
  if (tid < NCLS)
    sums[tid * DIM + d] = red[0][tid] + red[1][tid] + red[2][tid] + red[3][tid];
}

// K3 (fused k2+k3): per-block proto prologue (R1's verified form — kernel
// boundary gives coherence on sums/hist, no fences), then the 16-slab / 4-px-
// per-lane logits GEMM with a REGISTER-LEAN inner loop: running row pointer so
// the 4 pixel loads use one base + imm offsets (0/256/512/768 B), unroll 2.
// (R4's unroll-4 form needed ~16 live 64-bit addresses + 36 acc + 16 f-values
// -> at/over the 128-VGPR ceiling for 1024-thread blocks.)
__global__ void __launch_bounds__(1024) k3_fused(const float* __restrict__ sums,
                                                 const int* __restrict__ hist,
                                                 const float* __restrict__ proto,
                                                 const float* __restrict__ feat,
                                                 float* __restrict__ logits,
                                                 float* __restrict__ sumsq) {
  __shared__ float pl[DIM * 12];  // 36864 B: protoT, then 4x [9][256] combine regions
  __shared__ float cpart[32][NCLS];
  __shared__ float cnt[NCLS];
  __shared__ float red12[12][NCLS];
  __shared__ float invn[NCLS];
  int tid = threadIdx.x;

  // ---- prologue: counts from per-block hist ----
  if (tid < 288) {
    int c = tid % NCLS, g = tid / NCLS;  // g in 0..31
    int s = 0;
#pragma unroll
    for (int j = 0; j < 8; ++j) s += hist[(g * 8 + j) * NCLS + c];
    cpart[g][c] = (float)s;
  }
  __syncthreads();
  if (tid < NCLS) {
    float s = 0.f;
#pragma unroll
    for (int g = 0; g < 32; ++g) s += cpart[g][tid];
    cnt[tid] = s;
  }
  __syncthreads();

  // ---- prologue: protos = l2norm(0.99*mean + 0.01*proto) -> pl[d*12 + c] ----
  float v[NCLS];
  if (tid < DIM) {
#pragma unroll
    for (int c = 0; c < NCLS; ++c)
      v[c] = 0.99f * (sums[c * DIM + tid] / cnt[c]) + 0.01f * proto[c * DIM + tid];
    int lane = tid & 63, w = tid >> 6;  // w in 0..11
#pragma unroll
    for (int c = 0; c < NCLS; ++c) {
      float q = waveReduceSum(v[c] * v[c]);
      if (lane == 0) red12[w][c] = q;
    }
  }
  __syncthreads();
  if (tid < NCLS) {
    float t = 0.f;
#pragma unroll
    for (int w2 = 0; w2 < 12; ++w2) t += red12[w2][tid];
    invn[tid] = 1.f / fmaxf(sqrtf(t), 1e-12f);
  }
  __syncthreads();
  if (tid < DIM) {
#pragma unroll
    for (int c = 0; c < NCLS; ++c) pl[tid * 12 + c] = v[c] * invn[c];
  }
  __syncthreads();

  // ---- main: 16 dim-slabs (one wave each, 48 dims), 4 px/lane ----
  int s = tid >> 6, lane = tid & 63;
  int n0 = blockIdx.x * 256;
  int b = n0 >> 14, ppb = n0 & 16383;  // whole block in one batch (256 | 16384)
  const float* fr = feat + ((size_t)(b * DIM + s * 48)) * 16384 + ppb + lane;
  const float* pp = pl + (size_t)s * 48 * 12;
  float a[NCLS][4];
#pragma unroll
  for (int c = 0; c < NCLS; ++c)
#pragma unroll
    for (int j = 0; j < 4; ++j) a[c][j] = 0.f;

#pragma unroll 2
  for (int dd = 0; dd < 48; ++dd) {
    float f0 = fr[0], f1 = fr[64], f2 = fr[128], f3 = fr[192];
    float4 q0 = *(const float4*)pp;
    float4 q1 = *(const float4*)(pp + 4);
    float q8 = pp[8];
    float pcs[NCLS] = {q0.x, q0.y, q0.z, q0.w, q1.x, q1.y, q1.z, q1.w, q8};
#pragma unroll
    for (int c = 0; c < NCLS; ++c) {
      a[c][0] += pcs[c] * f0;
      a[c][1] += pcs[c] * f1;
      a[c][2] += pcs[c] * f2;
      a[c][3] += pcs[c] * f3;
    }
    fr += 16384;
    pp += 12;
  }
  __syncthreads();  // proto reads done; pl reusable

  // ---- plain-write combine tree (NO fp32 LDS atomics: CAS-loop hazard, R3) ----
#pragma unroll
  for (int r = 1; r <= 3; ++r) {
    if (s >= 4 * r && s < 4 * r + 4) {
      float* rp = pl + (size_t)(s - 4 * r) * 2304 + lane;
#pragma unroll
      for (int c = 0; c < NCLS; ++c)
#pragma unroll
        for (int j = 0; j < 4; ++j) rp[c * 256 + 64 * j] = a[c][j];
    }
    __syncthreads();
    if (s < 4) {
      const float* rp = pl + (size_t)s * 2304 + lane;
#pragma unroll
      for (int c = 0; c < NCLS; ++c)
#pragma unroll
        for (int j = 0; j < 4; ++j) a[c][j] += rp[c * 256 + 64 * j];
    }
    __syncthreads();
  }
  if (s >= 1 && s < 4) {
    float* rp = pl + (size_t)(s - 1) * 2304 + lane;
#pragma unroll
    for (int c = 0; c < NCLS; ++c)
#pragma unroll
      for (int j = 0; j < 4; ++j) rp[c * 256 + 64 * j] = a[c][j];
  }
  __syncthreads();
  if (s == 0) {
#pragma unroll
    for (int q = 0; q < 3; ++q) {
      const float* rp = pl + (size_t)q * 2304 + lane;
#pragma unroll
      for (int c = 0; c < NCLS; ++c)
#pragma unroll
        for (int j = 0; j < 4; ++j) a[c][j] += rp[c * 256 + 64 * j];
    }
    float ss[NCLS];
#pragma unroll
    for (int c = 0; c < NCLS; ++c) {
#pragma unroll
      for (int j = 0; j < 4; ++j)
        logits[(size_t)c * NPIX + n0 + lane + 64 * j] = a[c][j];
      float qq = a[c][0] * a[c][0] + a[c][1] * a[c][1] +
                 a[c][2] * a[c][2] + a[c][3] * a[c][3];
      ss[c] = waveReduceSum(qq);
    }
    if (lane == 0) {
#pragma unroll
      for (int c = 0; c < NCLS; ++c) atomicAdd(&sumsq[c], ss[c]);
    }
  }
}

// K5: per-pixel loss + fused finalize via done-ticket.
__global__ void k5_loss(const float4* __restrict__ logits4, const uchar4* __restrict__ lab4,
                        const float* __restrict__ sumsq, float* __restrict__ lossacc,
                        unsigned int* __restrict__ done, float* __restrict__ out) {
  int t = blockIdx.x * 256 + threadIdx.x;  // float4 index over 16384
  int tid = threadIdx.x;
  float scale[NCLS];
#pragma unroll
  for (int c = 0; c < NCLS; ++c) scale[c] = 10.f / fmaxf(sqrtf(sumsq[c]), 1e-12f);
  float arr[NCLS][4];
#pragma unroll
  for (int c = 0; c < NCLS; ++c) {
    float4 v = logits4[(size_t)c * 16384 + t];
    arr[c][0] = v.x; arr[c][1] = v.y; arr[c][2] = v.z; arr[c][3] = v.w;
  }
  uchar4 lb = lab4[t];
  int lv[4] = {lb.x, lb.y, lb.z, lb.w};
  float lsum = 0.f;
#pragma unroll
  for (int j = 0; j < 4; ++j) {
    int l = lv[j];
    int lc = (l == 7) ? 6 : l;
    float sumE = 0.f, picked = 0.f;
#pragma unroll
    for (int c = 0; c < NCLS; ++c) {
      float pf = (c == 2) ? ((lc == 2) ? 1.f : 0.f) : arr[c][j] * scale[c];
      sumE += __expf(pf);
      picked += (c == lc) ? pf : 0.f;
    }
    lsum += __logf(sumE) - picked;
  }
  lsum = waveReduceSum(lsum);
  __shared__ float red[4];
  int lane = tid & 63, w = tid >> 6;
  if (lane == 0) red[w] = lsum;
  __syncthreads();
  if (tid == 0) {
    atomicAdd(lossacc, red[0] + red[1] + red[2] + red[3]);
    __threadfence();
    unsigned int ticket = atomicAdd(done, 1u);
    if (ticket == gridDim.x - 1) {
      __threadfence();
      float total = __hip_atomic_load(lossacc, __ATOMIC_ACQUIRE, __HIP_MEMORY_SCOPE_AGENT);
      out[0] = total * (1.f / (float)NPIX);
    }
  }
}

extern "C" void kernel_launch(void* const* d_in, const int* in_sizes, int n_in,
                              void* d_out, int out_size, void* d_ws, size_t ws_size,
                              hipStream_t stream) {
  // inputs: 0=cls_score (unused), 1=label, 2=gt_lucas (unused), 3=features, 4=prototypes
  const int* label = (const int*)d_in[1];
  const float* feat = (const float*)d_in[3];
  const float* proto = (const float*)d_in[4];
  char* ws = (char*)d_ws;
  unsigned char* lab = (unsigned char*)(ws + OFF_LAB);
  int* hist = (int*)(ws + OFF_HIST);
  float* sums = (float*)(ws + OFF_SUMS);
  float* sumsq = (float*)(ws + OFF_SUMSQ);
  float* lossacc = (float*)(ws + OFF_LOSS);
  unsigned int* done = (unsigned int*)(ws + OFF_DONE);
  float* logits = (float*)(ws + OFF_LOGITS);

  k0_lab<<<NPIX / 256, 256, 0, stream>>>(label, lab, hist, sumsq, lossacc, done);
  k1_segsum<<<DIM, 256, 0, stream>>>((const float4*)feat, (const uchar4*)lab, sums);
  k3_fused<<<NPIX / 256, 1024, 0, stream>>>(sums, hist, proto, feat, logits, sumsq);
  k5_loss<<<64, 256, 0, stream>>>((const float4*)logits, (const uchar4*)lab, sumsq, lossacc,
                                  done, (float*)d_out);
}

// Round 6
// 101.993 us; speedup vs baseline: 1.2158x; 1.2158x over previous
//
#include <hip/hip_runtime.h>
#include <math.h>

#define NCLS 9
#define DIM 768
#define NPIX 65536   // 4 * 128 * 128

// ---- workspace layout (bytes), no memset needed ----
#define OFF_LAB     ((size_t)0)        // uchar[65536]          = 65536
#define OFF_HIST    ((size_t)65536)    // int[256*9]            = 9216   -> 74752
#define OFF_SUMS    ((size_t)74752)    // float[9*768]          = 27648  -> 102400
#define OFF_SUMSQ   ((size_t)102400)   // float[16] (zeroed by k0)
#define OFF_LOSS    ((size_t)102464)   // float[4]  (zeroed by k0)
#define OFF_DONE    ((size_t)102480)   // uint[4]   (zeroed by k0, k5 ticket)
#define OFF_LOGITS  ((size_t)139392)   // float[9*65536]        = 2359296 -> 2498688
// total ~2.5 MB

__device__ __forceinline__ float waveReduceSum(float v) {
#pragma unroll
  for (int off = 32; off > 0; off >>= 1) v += __shfl_down(v, off, 64);
  return v;
}

// K0: downsample labels -> uchar lab[n]; per-block histogram -> hist[block][9];
// block 0 zero-inits sumsq/lossacc/done for downstream kernels.
__global__ void k0_lab(const int* __restrict__ label, unsigned char* __restrict__ lab,
                       int* __restrict__ hist, float* __restrict__ sumsq,
                       float* __restrict__ lossacc, unsigned int* __restrict__ done) {
  __shared__ int h[NCLS];
  int tid = threadIdx.x;
  if (tid < NCLS) h[tid] = 0;
  __syncthreads();
  int n = blockIdx.x * 256 + tid;
  int b = n >> 14, r = (n >> 7) & 127, cc = n & 127;
  int c = label[b * 262144 + r * 2048 + cc * 4];
  lab[n] = (unsigned char)c;
  atomicAdd(&h[c], 1);
  if (blockIdx.x == 0) {
    if (tid < 16) sumsq[tid] = 0.f;
    else if (tid == 16) lossacc[0] = 0.f;
    else if (tid == 17) done[0] = 0u;
  }
  __syncthreads();
  if (tid < NCLS) hist[blockIdx.x * NCLS + tid] = h[tid];
}

// K1: per-class segment sums. One block per feature dim d. Pure streaming — NO
// fences/tickets here (agent-scope __threadfence in every block was a 5x
// slowdown in R2: forces L2 writebacks on non-coherent XCD L2s).
__global__ void k1_segsum(const float4* __restrict__ feat4, const uchar4* __restrict__ lab4,
                          float* __restrict__ sums) {
  int d = blockIdx.x;
  int tid = threadIdx.x;
  float acc[NCLS];
#pragma unroll
  for (int k = 0; k < NCLS; ++k) acc[k] = 0.f;
  for (int b = 0; b < 4; ++b) {
    const float4* fp = feat4 + (size_t)(b * DIM + d) * 4096;
    const uchar4* lp = lab4 + b * 4096;
#pragma unroll 4
    for (int i = 0; i < 16; ++i) {
      int p = tid + i * 256;
      float4 f = fp[p];
      uchar4 l = lp[p];
      int lx = l.x, ly = l.y, lz = l.z, lw = l.w;
#pragma unroll
      for (int k = 0; k < NCLS; ++k) {
        acc[k] += (lx == k) ? f.x : 0.f;
        acc[k] += (ly == k) ? f.y : 0.f;
        acc[k] += (lz == k) ? f.z : 0.f;
        acc[k] += (lw == k) ? f.w : 0.f;
      }
    }
  }
  __shared__ float red[4][NCLS];
#pragma unroll
  for (int k = 0; k < NCLS; ++k) acc[k] = waveReduceSum(acc[k]);
  int lane = tid & 63, w = tid >> 6;
  if (lane == 0) {
#pragma unroll
    for (int k = 0; k < NCLS; ++k) red[w][k] = acc[k];
  }
  __syncthreads();
  if (tid < NCLS)
    sums[tid * DIM + d] = red[0][tid] + red[1][tid] + red[2][tid] + red[3][tid];
}

// K3 (fused k2+k3): per-block proto prologue, then logits GEMM with 8 dim-groups
// (2 waves each, 96 dims) and 2 px/lane. Accumulators a[9][2]=18 VGPR keeps the
// live set under 64 VGPR; __launch_bounds__(1024, 8) forces 8 waves/EU = 32
// waves/CU = 2 blocks/CU residency (R3-R5's a[9][4]=36-acc form exceeded 64
// VGPR -> 1 block/CU -> latency-exposed prologue/epilogue, ~25us slower).
// LDS-pipe work per wave is still 2x less than the 1px/thread form.
__global__ void __launch_bounds__(1024, 8) k3_fused(const float* __restrict__ sums,
                                                    const int* __restrict__ hist,
                                                    const float* __restrict__ proto,
                                                    const float* __restrict__ feat,
                                                    float* __restrict__ logits,
                                                    float* __restrict__ sumsq) {
  __shared__ float pl[DIM * 12];  // 36864 B: protoT, then 4x [9][256] combine regions
  __shared__ float cpart[32][NCLS];
  __shared__ float cnt[NCLS];
  __shared__ float red12[12][NCLS];
  __shared__ float invn[NCLS];
  __shared__ float red2[2][NCLS];
  int tid = threadIdx.x;

  // ---- prologue: counts from per-block hist ----
  if (tid < 288) {
    int c = tid % NCLS, g = tid / NCLS;  // g in 0..31
    int s = 0;
#pragma unroll
    for (int j = 0; j < 8; ++j) s += hist[(g * 8 + j) * NCLS + c];
    cpart[g][c] = (float)s;
  }
  __syncthreads();
  if (tid < NCLS) {
    float s = 0.f;
#pragma unroll
    for (int g = 0; g < 32; ++g) s += cpart[g][tid];
    cnt[tid] = s;
  }
  __syncthreads();

  // ---- prologue: protos = l2norm(0.99*mean + 0.01*proto) -> pl[d*12 + c] ----
  float v[NCLS];
  if (tid < DIM) {
#pragma unroll
    for (int c = 0; c < NCLS; ++c)
      v[c] = 0.99f * (sums[c * DIM + tid] / cnt[c]) + 0.01f * proto[c * DIM + tid];
    int lane = tid & 63, w = tid >> 6;  // w in 0..11
#pragma unroll
    for (int c = 0; c < NCLS; ++c) {
      float q = waveReduceSum(v[c] * v[c]);
      if (lane == 0) red12[w][c] = q;
    }
  }
  __syncthreads();
  if (tid < NCLS) {
    float t = 0.f;
#pragma unroll
    for (int w2 = 0; w2 < 12; ++w2) t += red12[w2][tid];
    invn[tid] = 1.f / fmaxf(sqrtf(t), 1e-12f);
  }
  __syncthreads();
  if (tid < DIM) {
#pragma unroll
    for (int c = 0; c < NCLS; ++c) pl[tid * 12 + c] = v[c] * invn[c];
  }
  __syncthreads();

  // ---- main: 8 groups (2 waves each, 96 dims), 2 px/lane ----
  int grp = tid >> 7, g = tid & 127;   // group index; pixel within first half
  int n0 = blockIdx.x * 256;
  int b = n0 >> 14, ppb = n0 & 16383;  // whole block in one batch (256 | 16384)
  const float* fr = feat + ((size_t)(b * DIM + grp * 96)) * 16384 + ppb + g;
  const float* pp = pl + (size_t)grp * 96 * 12;
  float a[NCLS][2];
#pragma unroll
  for (int c = 0; c < NCLS; ++c) { a[c][0] = 0.f; a[c][1] = 0.f; }

#pragma unroll 2
  for (int dd = 0; dd < 96; ++dd) {
    float f0 = fr[0], f1 = fr[128];
    float4 q0 = *(const float4*)pp;
    float4 q1 = *(const float4*)(pp + 4);
    float q8 = pp[8];
    float pcs[NCLS] = {q0.x, q0.y, q0.z, q0.w, q1.x, q1.y, q1.z, q1.w, q8};
#pragma unroll
    for (int c = 0; c < NCLS; ++c) {
      a[c][0] += pcs[c] * f0;
      a[c][1] += pcs[c] * f1;
    }
    fr += 16384;
    pp += 12;
  }
  __syncthreads();  // proto reads done; pl reusable

  // ---- plain-write combine tree (NO fp32 LDS atomics: CAS-loop hazard, R3) ----
  // round 1: groups 4-7 write regions 0-3; groups 0-3 accumulate
  if (grp >= 4) {
    float* rp = pl + (size_t)(grp - 4) * 2304 + g;
#pragma unroll
    for (int c = 0; c < NCLS; ++c) {
      rp[c * 256] = a[c][0];
      rp[c * 256 + 128] = a[c][1];
    }
  }
  __syncthreads();
  if (grp < 4) {
    const float* rp = pl + (size_t)grp * 2304 + g;
#pragma unroll
    for (int c = 0; c < NCLS; ++c) {
      a[c][0] += rp[c * 256];
      a[c][1] += rp[c * 256 + 128];
    }
  }
  __syncthreads();
  // round 2: groups 1-3 write regions 0-2; group 0 accumulates + epilogue
  if (grp >= 1 && grp < 4) {
    float* rp = pl + (size_t)(grp - 1) * 2304 + g;
#pragma unroll
    for (int c = 0; c < NCLS; ++c) {
      rp[c * 256] = a[c][0];
      rp[c * 256 + 128] = a[c][1];
    }
  }
  __syncthreads();
  if (grp == 0) {
#pragma unroll
    for (int q = 0; q < 3; ++q) {
      const float* rp = pl + (size_t)q * 2304 + g;
#pragma unroll
      for (int c = 0; c < NCLS; ++c) {
        a[c][0] += rp[c * 256];
        a[c][1] += rp[c * 256 + 128];
      }
    }
    float ss[NCLS];
#pragma unroll
    for (int c = 0; c < NCLS; ++c) {
      logits[(size_t)c * NPIX + n0 + g] = a[c][0];
      logits[(size_t)c * NPIX + n0 + 128 + g] = a[c][1];
      ss[c] = waveReduceSum(a[c][0] * a[c][0] + a[c][1] * a[c][1]);
    }
    int lane = tid & 63, w = tid >> 6;  // w in {0,1}
    if (lane == 0) {
#pragma unroll
      for (int c = 0; c < NCLS; ++c) red2[w][c] = ss[c];
    }
  }
  __syncthreads();
  if (tid < NCLS) atomicAdd(&sumsq[tid], red2[0][tid] + red2[1][tid]);
}

// K5: per-pixel loss + fused finalize via done-ticket.
__global__ void k5_loss(const float4* __restrict__ logits4, const uchar4* __restrict__ lab4,
                        const float* __restrict__ sumsq, float* __restrict__ lossacc,
                        unsigned int* __restrict__ done, float* __restrict__ out) {
  int t = blockIdx.x * 256 + threadIdx.x;  // float4 index over 16384
  int tid = threadIdx.x;
  float scale[NCLS];
#pragma unroll
  for (int c = 0; c < NCLS; ++c) scale[c] = 10.f / fmaxf(sqrtf(sumsq[c]), 1e-12f);
  float arr[NCLS][4];
#pragma unroll
  for (int c = 0; c < NCLS; ++c) {
    float4 v = logits4[(size_t)c * 16384 + t];
    arr[c][0] = v.x; arr[c][1] = v.y; arr[c][2] = v.z; arr[c][3] = v.w;
  }
  uchar4 lb = lab4[t];
  int lv[4] = {lb.x, lb.y, lb.z, lb.w};
  float lsum = 0.f;
#pragma unroll
  for (int j = 0; j < 4; ++j) {
    int l = lv[j];
    int lc = (l == 7) ? 6 : l;
    float sumE = 0.f, picked = 0.f;
#pragma unroll
    for (int c = 0; c < NCLS; ++c) {
      float pf = (c == 2) ? ((lc == 2) ? 1.f : 0.f) : arr[c][j] * scale[c];
      sumE += __expf(pf);
      picked += (c == lc) ? pf : 0.f;
    }
    lsum += __logf(sumE) - picked;
  }
  lsum = waveReduceSum(lsum);
  __shared__ float red[4];
  int lane = tid & 63, w = tid >> 6;
  if (lane == 0) red[w] = lsum;
  __syncthreads();
  if (tid == 0) {
    atomicAdd(lossacc, red[0] + red[1] + red[2] + red[3]);
    __threadfence();
    unsigned int ticket = atomicAdd(done, 1u);
    if (ticket == gridDim.x - 1) {
      __threadfence();
      float total = __hip_atomic_load(lossacc, __ATOMIC_ACQUIRE, __HIP_MEMORY_SCOPE_AGENT);
      out[0] = total * (1.f / (float)NPIX);
    }
  }
}

extern "C" void kernel_launch(void* const* d_in, const int* in_sizes, int n_in,
                              void* d_out, int out_size, void* d_ws, size_t ws_size,
                              hipStream_t stream) {
  // inputs: 0=cls_score (unused), 1=label, 2=gt_lucas (unused), 3=features, 4=prototypes
  const int* label = (const int*)d_in[1];
  const float* feat = (const float*)d_in[3];
  const float* proto = (const float*)d_in[4];
  char* ws = (char*)d_ws;
  unsigned char* lab = (unsigned char*)(ws + OFF_LAB);
  int* hist = (int*)(ws + OFF_HIST);
  float* sums = (float*)(ws + OFF_SUMS);
  float* sumsq = (float*)(ws + OFF_SUMSQ);
  float* lossacc = (float*)(ws + OFF_LOSS);
  unsigned int* done = (unsigned int*)(ws + OFF_DONE);
  float* logits = (float*)(ws + OFF_LOGITS);

  k0_lab<<<NPIX / 256, 256, 0, stream>>>(label, lab, hist, sumsq, lossacc, done);
  k1_segsum<<<DIM, 256, 0, stream>>>((const float4*)feat, (const uchar4*)lab, sums);
  k3_fused<<<NPIX / 256, 1024, 0, stream>>>(sums, hist, proto, feat, logits, sumsq);
  k5_loss<<<64, 256, 0, stream>>>((const float4*)logits, (const uchar4*)lab, sumsq, lossacc,
                                  done, (float*)d_out);
}